// Round 1
// baseline (76.472 us; speedup 1.0000x reference)
//
#include <hip/hip_runtime.h>

// LiftingScheme reduces algebraically to a plain 3x3 same-padding conv2d:
//   out[n,o,i,j] = sum_c sum_{kh,kw} w[o,c,kh,kw] * x[n,c,i+kh-1,j+kw-1]
// (the predict/update coefficients p0..p3, u0..u4 cancel exactly to w).
//
// N=2, C=32, H=W=56, O=64, fp32. 0.231 GFLOP, ~2.5 MB footprint.
// Round-1: fp32 vector kernel, LDS-staged x tile + weight tile.
// Block = 256 thr (4 waves) handles (n, row-pair, 8 o). Each lane: 2 cols x 2 o,
// 4-col x 3-row register window -> 36 FMA per channel per lane.

namespace {
constexpr int Nn = 2, Cc = 32, Hh = 56, Ww = 56, Oo = 64;

__global__ __launch_bounds__(256)
void lifting_conv_kernel(const float* __restrict__ x,
                         const float* __restrict__ w,
                         float* __restrict__ out)
{
    // x tile: [C][4 padded rows][60 (58 used, stride 60 keeps 16B align)] = 30 KB
    __shared__ float xs[Cc * 4 * 60];
    // w tile: [8 o][C][12 (9 used, pad for aligned float4 reads)] = 12 KB
    __shared__ float ws[8 * Cc * 12];

    const int tid = threadIdx.x;
    const int og  = blockIdx.x;   // 0..7  -> o0 = 8*og
    const int ip  = blockIdx.y;   // 0..27 -> rows 2*ip, 2*ip+1
    const int n   = blockIdx.z;   // 0..1
    const int i0  = ip * 2;
    const int o0  = og * 8;

    // ---- stage x rows i0-1..i0+2 (zero-padded), cols -1..56 (zero-padded) ----
    for (int e = tid; e < Cc * 4 * 58; e += 256) {
        const int c   = e / (4 * 58);
        const int rem = e - c * (4 * 58);
        const int r   = rem / 58;
        const int jj  = rem - r * 58;
        const int h   = i0 - 1 + r;
        const int ws_ = jj - 1;
        float v = 0.0f;
        if ((unsigned)h < (unsigned)Hh && (unsigned)ws_ < (unsigned)Ww)
            v = x[((n * Cc + c) * Hh + h) * Ww + ws_];
        xs[(c * 4 + r) * 60 + jj] = v;
    }
    // ---- stage weights for this block's 8 output channels ----
    for (int e = tid; e < 8 * Cc * 9; e += 256) {
        const int o   = e / (Cc * 9);
        const int rem = e - o * (Cc * 9);
        const int c   = rem / 9;
        const int k   = rem - c * 9;
        ws[(o * Cc + c) * 12 + k] = w[((o0 + o) * Cc + c) * 9 + k];
    }
    __syncthreads();

    const int lane = tid & 63;
    const int wv   = tid >> 6;            // wave id 0..3 -> o pair
    if (lane >= 56) return;               // 56 active lanes per wave
    const int rsub = (lane >= 28) ? 1 : 0;
    const int cp   = lane - rsub * 28;    // column pair 0..27
    const int col0 = cp * 2;

    float a00 = 0.f, a01 = 0.f, a10 = 0.f, a11 = 0.f;  // [o_local][col]
    const float* xbase = &xs[rsub * 60 + col0];
    const float* wb0   = &ws[(wv * 2 + 0) * (Cc * 12)];
    const float* wb1   = &ws[(wv * 2 + 1) * (Cc * 12)];

    #pragma unroll 4
    for (int c = 0; c < Cc; ++c) {
        const float* xr = xbase + c * 240;
        // 3 rows x 4 cols register window (6x ds_read_b64, 8B-aligned)
        const float2 r0a = *(const float2*)(xr);
        const float2 r0b = *(const float2*)(xr + 2);
        const float2 r1a = *(const float2*)(xr + 60);
        const float2 r1b = *(const float2*)(xr + 62);
        const float2 r2a = *(const float2*)(xr + 120);
        const float2 r2b = *(const float2*)(xr + 122);

        // weights: broadcast reads (same addr across wave -> conflict-free)
        const float4 wA0 = *(const float4*)(wb0 + c * 12);
        const float4 wB0 = *(const float4*)(wb0 + c * 12 + 4);
        const float  wC0 = wb0[c * 12 + 8];
        a00 += wA0.x * r0a.x + wA0.y * r0a.y + wA0.z * r0b.x
             + wA0.w * r1a.x + wB0.x * r1a.y + wB0.y * r1b.x
             + wB0.z * r2a.x + wB0.w * r2a.y + wC0  * r2b.x;
        a01 += wA0.x * r0a.y + wA0.y * r0b.x + wA0.z * r0b.y
             + wA0.w * r1a.y + wB0.x * r1b.x + wB0.y * r1b.y
             + wB0.z * r2a.y + wB0.w * r2b.x + wC0  * r2b.y;

        const float4 wA1 = *(const float4*)(wb1 + c * 12);
        const float4 wB1 = *(const float4*)(wb1 + c * 12 + 4);
        const float  wC1 = wb1[c * 12 + 8];
        a10 += wA1.x * r0a.x + wA1.y * r0a.y + wA1.z * r0b.x
             + wA1.w * r1a.x + wB1.x * r1a.y + wB1.y * r1b.x
             + wB1.z * r2a.x + wB1.w * r2a.y + wC1  * r2b.x;
        a11 += wA1.x * r0a.y + wA1.y * r0b.x + wA1.z * r0b.y
             + wA1.w * r1a.y + wB1.x * r1b.x + wB1.y * r1b.y
             + wB1.z * r2a.y + wB1.w * r2b.x + wC1  * r2b.y;
    }

    const int row = i0 + rsub;
    const int ob0 = ((n * Oo + o0 + wv * 2 + 0) * Hh + row) * Ww + col0;
    const int ob1 = ob0 + Hh * Ww;
    float2 v0; v0.x = a00; v0.y = a01;
    float2 v1; v1.x = a10; v1.y = a11;
    *(float2*)(out + ob0) = v0;
    *(float2*)(out + ob1) = v1;
}
} // namespace

extern "C" void kernel_launch(void* const* d_in, const int* in_sizes, int n_in,
                              void* d_out, int out_size, void* d_ws, size_t ws_size,
                              hipStream_t stream)
{
    const float* x = (const float*)d_in[0];   // (2,32,56,56) fp32
    const float* w = (const float*)d_in[1];   // (64,32,3,3) fp32
    float* out = (float*)d_out;               // (2,64,56,56) fp32

    dim3 grid(8, 28, 2);  // (o-groups of 8, row-pairs, n) = 448 blocks
    lifting_conv_kernel<<<grid, 256, 0, stream>>>(x, w, out);
}

// Round 2
// 74.332 us; speedup vs baseline: 1.0288x; 1.0288x over previous
//
#include <hip/hip_runtime.h>

// LiftingScheme == plain 3x3 same-padding conv2d (predict/update coeffs cancel
// exactly to w): out[n,o,i,j] = sum_{c,kh,kw} w[o,c,kh,kw]*x[n,c,i+kh-1,j+kw-1]
//
// Round-2: round-1 was LDS-pipe-bound (~330-420 cyc/c per CU vs 144 cyc/c VALU
// wall). Changes:
//  1. 4 output channels per lane (2 cols x 4 o): same 6 ds_read_b64 x-reads
//     per c now feed 72 MACs (0.67 B/MAC) -> per-CU LDS ~116 cyc/c < VALU 144.
//  2. Weights via wave-uniform scalar loads (readfirstlane-forced SMEM path),
//     zero LDS slots spent on weights.
// Grid 224 blocks x 256 thr (4 waves), 1 block/CU, uniform load balance.

namespace {
constexpr int Cc = 32, Hh = 56, Ww = 56, Oo = 64;

__global__ __launch_bounds__(256)
void lifting_conv_kernel(const float* __restrict__ x,
                         const float* __restrict__ w,
                         float* __restrict__ out)
{
    // x tile: [C][4 padded rows][60 (58 used)] = 30 KB
    __shared__ float xs[Cc * 4 * 60];

    const int tid = threadIdx.x;
    const int og  = blockIdx.x;   // 0..3  -> o0 = 16*og
    const int ip  = blockIdx.y;   // 0..27 -> rows 2*ip, 2*ip+1
    const int n   = blockIdx.z;   // 0..1
    const int i0  = ip * 2;

    // ---- stage x rows i0-1..i0+2 (zero-padded), cols -1..56 (zero-padded) ----
    for (int e = tid; e < Cc * 4 * 58; e += 256) {
        const int c   = e / (4 * 58);
        const int rem = e - c * (4 * 58);
        const int r   = rem / 58;
        const int jj  = rem - r * 58;
        const int h   = i0 - 1 + r;
        const int col = jj - 1;
        float v = 0.0f;
        if ((unsigned)h < (unsigned)Hh && (unsigned)col < (unsigned)Ww)
            v = x[((n * Cc + c) * Hh + h) * Ww + col];
        xs[(c * 4 + r) * 60 + jj] = v;
    }
    __syncthreads();

    const int lane = tid & 63;
    const int wv   = tid >> 6;            // wave id 0..3 -> o quad
    if (lane >= 56) return;               // 56 active lanes per wave
    const int rsub = (lane >= 28) ? 1 : 0;
    const int cp   = lane - rsub * 28;    // column pair 0..27
    const int col0 = cp * 2;

    // wave-uniform output-channel base -> scalar (SMEM) weight loads
    const int o_base = __builtin_amdgcn_readfirstlane(og * 16 + wv * 4);
    const float* __restrict__ wb = w + (size_t)o_base * Cc * 9;

    float acc[4][2];
    #pragma unroll
    for (int i = 0; i < 4; ++i) { acc[i][0] = 0.f; acc[i][1] = 0.f; }

    const float* xbase = &xs[rsub * 60 + col0];

    #pragma unroll 2
    for (int c = 0; c < Cc; ++c) {
        const float* xr = xbase + c * 240;
        // 3 rows x 4 cols register window (6x ds_read_b64, 8B-aligned)
        const float2 r0a = *(const float2*)(xr);
        const float2 r0b = *(const float2*)(xr + 2);
        const float2 r1a = *(const float2*)(xr + 60);
        const float2 r1b = *(const float2*)(xr + 62);
        const float2 r2a = *(const float2*)(xr + 120);
        const float2 r2b = *(const float2*)(xr + 122);

        #pragma unroll
        for (int oo = 0; oo < 4; ++oo) {
            const float* wc = wb + (oo * Cc + c) * 9;   // wave-uniform address
            const float w0 = wc[0], w1 = wc[1], w2 = wc[2],
                        w3 = wc[3], w4 = wc[4], w5 = wc[5],
                        w6 = wc[6], w7 = wc[7], w8 = wc[8];
            acc[oo][0] += w0 * r0a.x + w1 * r0a.y + w2 * r0b.x
                        + w3 * r1a.x + w4 * r1a.y + w5 * r1b.x
                        + w6 * r2a.x + w7 * r2a.y + w8 * r2b.x;
            acc[oo][1] += w0 * r0a.y + w1 * r0b.x + w2 * r0b.y
                        + w3 * r1a.y + w4 * r1b.x + w5 * r1b.y
                        + w6 * r2a.y + w7 * r2b.x + w8 * r2b.y;
        }
    }

    const int row = i0 + rsub;
    #pragma unroll
    for (int oo = 0; oo < 4; ++oo) {
        float2 v; v.x = acc[oo][0]; v.y = acc[oo][1];
        *(float2*)(out + ((size_t)(n * Oo + o_base + oo) * Hh + row) * Ww + col0) = v;
    }
}
} // namespace

extern "C" void kernel_launch(void* const* d_in, const int* in_sizes, int n_in,
                              void* d_out, int out_size, void* d_ws, size_t ws_size,
                              hipStream_t stream)
{
    const float* x = (const float*)d_in[0];   // (2,32,56,56) fp32
    const float* w = (const float*)d_in[1];   // (64,32,3,3) fp32
    float* out = (float*)d_out;               // (2,64,56,56) fp32

    dim3 grid(4, 28, 2);  // (o-groups of 16, row-pairs, n) = 224 blocks
    lifting_conv_kernel<<<grid, 256, 0, stream>>>(x, w, out);
}